// Round 6
// baseline (280.214 us; speedup 1.0000x reference)
//
#include <hip/hip_runtime.h>
#include <hip/hip_bf16.h>

// Dense FFN: out = relu(x @ w1 + b1) @ w2 + b2
// x  [8192,1024] f32, w1 [1024,4096] f32, b1 [4096] f32,
// w2 [4096,1024] f32, b2 [1024] f32, out [8192,1024] f32.
// R6: LDS bandwidth is the measured binding pipe (96 b128 ops/iter ~1150cyc
// vs MFMA 620cyc; R2/R3/R5 all plateau at ~86-91us).  Remove B from LDS:
// prep stores weights in MFMA B-fragment-major layout (1KB unit = 16 n x
// 32 k, lane-ordered) so waves load B-frags as coalesced 1KB dwordx4 into
// registers, double-buffered one iteration ahead.  A stays in LDS (2x16KB
// dbuf via global_load_lds + XOR chunk swizzle), K-loop has ONE barrier per
// iter whose vmcnt(0) drains loads aged by a full compute phase.  Dispatch
// order by-fast per XCD keeps the live B working set cache-resident.

typedef __bf16 bf16;
typedef __bf16 bf16x4 __attribute__((ext_vector_type(4)));
typedef __bf16 bf16x8 __attribute__((ext_vector_type(8)));
typedef float  f32x4  __attribute__((ext_vector_type(4)));

#define BM 128
#define BN 128
#define BK 64

__device__ __forceinline__ void gload_lds16(const bf16* g, bf16* l) {
    __builtin_amdgcn_global_load_lds(
        (const __attribute__((address_space(1))) unsigned int*)g,
        (__attribute__((address_space(3))) unsigned int*)l,
        16, 0, 0);
}

// ---------------------------------------------------------------------------
// fused prep: cast x -> bf16 (row-major) ; w1, w2 -> B-fragment-major bf16.
// Frag layout: elem (k, n) lives at ((f*(K/32) + c)*64 + quad*16 + r)*8 + e
// where f=n/16, r=n%16, c=k/32, quad=(k%32)/8, e=k%8.
__device__ __forceinline__ void transpose_tile_frag(
    const float* __restrict__ in, bf16* __restrict__ out,
    int K, int N, int bx, int by, int t, bf16 (*tile)[72])
{
    const int k0 = by * 64;
    const int n0 = bx * 64;
    const int lr = t >> 4;          // 0..15
    const int lc = (t & 15) << 2;   // 0,4,..60
#pragma unroll
    for (int p = 0; p < 4; ++p) {
        int k = p * 16 + lr;
        float4 v = *(const float4*)(in + (size_t)(k0 + k) * N + n0 + lc);
        tile[lc + 0][k] = (bf16)v.x;
        tile[lc + 1][k] = (bf16)v.y;
        tile[lc + 2][k] = (bf16)v.z;
        tile[lc + 3][k] = (bf16)v.w;
    }
    __syncthreads();
    const int KC = K >> 5;
    const int wr = t >> 3;          // n_local 0..31 (+32 second pass)
    const int wc = (t & 7) << 3;    // k_local 0,8,..56
#pragma unroll
    for (int p = 0; p < 2; ++p) {
        int n = p * 32 + wr;
        int gn = n0 + n, gk = k0 + wc;
        int f = gn >> 4, r = gn & 15;
        int c = gk >> 5, quad = (gk >> 3) & 3;
        size_t off = ((size_t)((f * KC + c) * 64 + quad * 16 + r)) << 3;
        *(bf16x8*)(out + off) = *(const bf16x8*)&tile[n][wc];
    }
}

__global__ __launch_bounds__(256) void prep(
    const float* __restrict__ x,  bf16* __restrict__ xb,
    const float* __restrict__ w1, bf16* __restrict__ w1t,
    const float* __restrict__ w2, bf16* __restrict__ w2t)
{
    __shared__ __align__(16) bf16 tile[64][72];
    const int b = blockIdx.x;
    const int t = threadIdx.x;
    if (b < 8192) {                      // cast x: 4 f32/thread
        int i = b * 256 + t;
        float4 v = ((const float4*)x)[i];
        bf16x4 o;
        o.x = (bf16)v.x; o.y = (bf16)v.y; o.z = (bf16)v.z; o.w = (bf16)v.w;
        ((bf16x4*)xb)[i] = o;
    } else if (b < 9216) {               // w1 [1024][4096] -> frag layout
        int b2 = b - 8192;
        transpose_tile_frag(w1, w1t, 1024, 4096, b2 & 63, b2 >> 6, t, tile);
    } else {                             // w2 [4096][1024] -> frag layout
        int b2 = b - 9216;
        transpose_tile_frag(w2, w2t, 4096, 1024, b2 & 15, b2 >> 4, t, tile);
    }
}

// ---------------------------------------------------------------------------
// C[m][n] = sum_k A[m][k] * B[k][n]  (+bias, opt relu)
// A [M][K] bf16 row-major; Bf = B in fragment-major layout (see prep).
// Block = 256 thr = 4 waves, tile 128x128, BK=64.  Wave w -> 64x64 subtile
// (w>>1, w&1).  A: LDS double-buffer (global_load_lds, XOR chunk swizzle,
// 0 conflicts).  B: registers, 8x 1KB coalesced loads/iter, double-buffered
// one iteration ahead.  One barrier per iteration.
template <int FUSE_RELU_BF16, int K, int N>
__global__ __launch_bounds__(256, 2) void gemm_bt(
    const bf16* __restrict__ A, const bf16* __restrict__ Bf,
    const float* __restrict__ bias, void* __restrict__ Cout)
{
    constexpr int KC = K >> 5;          // 32-elem k-chunks
    constexpr int T  = K / BK;          // even (16 or 64)
    __shared__ __align__(16) bf16 As[2][BM * BK];   // 2 x 16 KiB

    // XCD-aware decode, by-fast: consecutive blocks on an XCD share bx.
    const int lid = blockIdx.x;
    const int xcd = lid & 7;
    const int i2  = lid >> 3;
    const int bx  = i2 >> 3;            // slow
    const int by  = (i2 & 7) * 8 + xcd; // fast (8 M-strips per XCD)

    const int tid  = threadIdx.x;
    const int wave = tid >> 6;
    const int lane = tid & 63;

    // ---- A staging: wave w covers rows [w*32, w*32+32), 4 b128 DMAs.
    const int l8 = lane >> 3;
    const int c8 = lane & 7;
    const int swc = (c8 ^ l8) << 3;     // swizzled global chunk offset
    const bf16* gA[4];
#pragma unroll
    for (int g = 0; g < 4; ++g)
        gA[g] = A + ((size_t)by * BM + wave * 32 + g * 8 + l8) * K + swc;
    const int lofsA = (wave * 32) * BK + lane * 8;

    const int wm   = (wave >> 1) << 6;
    const int wn   = (wave & 1) << 6;
    const int quad = lane >> 4;
    const int r    = lane & 15;
    const int r7   = lane & 7;

    // ---- B fragment pointer: f0 = bx*8 + (wave&1)*4
    const int f0 = bx * 8 + (wave & 1) * 4;
    const bf16* pB = Bf + (size_t)f0 * KC * 512 + lane * 8;

    f32x4  acc[4][4] = {};
    bf16x8 rB[2][8];                    // [set][jj*2+h]

    auto stageA = [&](int lb) {
#pragma unroll
        for (int g = 0; g < 4; ++g) {
            gload_lds16(gA[g], &As[lb][lofsA + g * (8 * BK)]);
            gA[g] += BK;
        }
    };
    auto prefB = [&](int set) {
#pragma unroll
        for (int jj = 0; jj < 4; ++jj)
#pragma unroll
            for (int h = 0; h < 2; ++h)
                rB[set][jj * 2 + h] =
                    *(const bf16x8*)(pB + ((size_t)jj * KC + h) * 512);
        pB += 1024;                     // advance 2 k-chunks
    };
    auto compute = [&](int lb, int set) {
#pragma unroll
        for (int h = 0; h < 2; ++h) {
            const int ch = ((h * 4 + quad) ^ r7) << 3;
            bf16x8 af[4];
#pragma unroll
            for (int i = 0; i < 4; ++i)
                af[i] = *(const bf16x8*)&As[lb][(wm + i * 16 + r) * BK + ch];
#pragma unroll
            for (int i = 0; i < 4; ++i)
#pragma unroll
                for (int jj = 0; jj < 4; ++jj)
                    acc[i][jj] = __builtin_amdgcn_mfma_f32_16x16x32_bf16(
                        af[i], rB[set][jj * 2 + h], acc[i][jj], 0, 0, 0);
        }
    };

    stageA(0);
    prefB(0);
    __syncthreads();                    // tile 0 resident
    for (int t = 0; t < T; t += 2) {
        stageA(1);                      // tile t+1 (always exists: t<=T-2)
        prefB(1);
        compute(0, 0);
        __syncthreads();                // drains t+1 loads (aged by compute)
        if (t + 2 < T) { stageA(0); prefB(0); }
        compute(1, 1);
        __syncthreads();
    }

    // epilogue: C/D layout col = lane&15, row = quad*4 + reg
    const int m_base = by * BM + wm + quad * 4;
    const int n_base = bx * BN + wn + r;
    float bv[4];
#pragma unroll
    for (int jj = 0; jj < 4; ++jj) bv[jj] = bias[n_base + jj * 16];

    if (FUSE_RELU_BF16) {
        bf16* Cb = (bf16*)Cout;
#pragma unroll
        for (int i = 0; i < 4; ++i) {
#pragma unroll
            for (int p = 0; p < 4; ++p) {
                size_t row = (size_t)(m_base + i * 16 + p) * (size_t)N;
#pragma unroll
                for (int jj = 0; jj < 4; ++jj) {
                    float v = acc[i][jj][p] + bv[jj];
                    v = v > 0.f ? v : 0.f;
                    Cb[row + n_base + jj * 16] = (bf16)v;
                }
            }
        }
    } else {
        float* Cf = (float*)Cout;
#pragma unroll
        for (int i = 0; i < 4; ++i) {
#pragma unroll
            for (int p = 0; p < 4; ++p) {
                size_t row = (size_t)(m_base + i * 16 + p) * (size_t)N;
#pragma unroll
                for (int jj = 0; jj < 4; ++jj) {
                    Cf[row + n_base + jj * 16] = acc[i][jj][p] + bv[jj];
                }
            }
        }
    }
}

// ---------------------------------------------------------------------------
extern "C" void kernel_launch(void* const* d_in, const int* in_sizes, int n_in,
                              void* d_out, int out_size, void* d_ws, size_t ws_size,
                              hipStream_t stream)
{
    const float* x  = (const float*)d_in[0];  // [8192,1024]
    const float* w1 = (const float*)d_in[1];  // [1024,4096]
    const float* b1 = (const float*)d_in[2];  // [4096]
    const float* w2 = (const float*)d_in[3];  // [4096,1024]
    const float* b2 = (const float*)d_in[4];  // [1024]
    float* out = (float*)d_out;               // [8192,1024]

    const int M = 8192, D = 1024, W = 4096;

    char* ws = (char*)d_ws;
    bf16* xb  = (bf16*)(ws);                           // 16 MiB: [8192,1024]
    bf16* w1t = (bf16*)(ws + (size_t)(16 << 20));      //  8 MiB: frag layout
    bf16* w2t = (bf16*)(ws + (size_t)(24 << 20));      //  8 MiB: frag layout
    bf16* h   = (bf16*)(ws + (size_t)(32 << 20));      // 64 MiB: [8192,4096]

    // 1. fused prep
    prep<<<8192 + 1024 + 1024, 256, 0, stream>>>(x, xb, w1, w1t, w2, w2t);

    // 2. h = relu(xb @ w1 + b1), bf16  [M][W]   grid 2048
    gemm_bt<1, 1024, 4096><<<(W / BN) * (M / BM), 256, 0, stream>>>(
        xb, w1t, b1, (void*)h);

    // 3. out = h @ w2 + b2, f32  [M][D]         grid 512
    gemm_bt<0, 4096, 1024><<<(D / BN) * (M / BM), 256, 0, stream>>>(
        h, w2t, b2, (void*)out);
}